// Round 11
// baseline (801.422 us; speedup 1.0000x reference)
//
#include <hip/hip_runtime.h>

#define NN 50000
#define EE 800000
#define ELLW 64
#define BN_EPS 1e-5f

// ---------------------------------------------------------------- zero ints
__global__ __launch_bounds__(256) void zero_i32(int* __restrict__ p, int n) {
  int i = blockIdx.x * 256 + threadIdx.x;
  if (i < n) p[i] = 0;
}

// ------------------------------------- build ELL: ell[d][pos] = s, deg[d]++
__global__ __launch_bounds__(256) void fill_ell(const int* __restrict__ src,
                                                const int* __restrict__ dst,
                                                int* __restrict__ deg,
                                                int* __restrict__ ell) {
  int e = blockIdx.x * 256 + threadIdx.x;
  if (e < EE) {
    int d = dst[e];
    int pos = atomicAdd(&deg[d], 1);
    if (pos < ELLW) ell[(size_t)d * ELLW + pos] = src[e];
  }
}

// -------- fused: agg = h + sum_{in-edges} h[src];  hout = MLP(agg)
// persistent blocks; one wave per node; float4 gather, exec-mask-predicated
// so exactly dg rows are fetched (condition uniform per 16-lane group)
__global__ __launch_bounds__(512) void mlp_fused(const float* __restrict__ h,
                                                 const int* __restrict__ deg,
                                                 const int* __restrict__ ell,
                                                 const float* __restrict__ Wa,
                                                 const float* __restrict__ ba,
                                                 const float* __restrict__ g,
                                                 const float* __restrict__ be,
                                                 const float* __restrict__ Wb,
                                                 const float* __restrict__ bb,
                                                 float* __restrict__ hout) {
  __shared__ float lA[4096], lB[4096], lba[64], lbb[64];
  // fold BN scale into lA and bias
  for (int i = threadIdx.x; i < 4096; i += 512) {
    float sc = g[i & 63] * (1.0f / sqrtf(1.0f + BN_EPS));
    lA[i] = Wa[i] * sc;
    lB[i] = Wb[i];
  }
  if (threadIdx.x < 64) {
    float sc = g[threadIdx.x] * (1.0f / sqrtf(1.0f + BN_EPS));
    lba[threadIdx.x] = fmaf(ba[threadIdx.x], sc, be[threadIdx.x]);
    lbb[threadIdx.x] = bb[threadIdx.x];
  }
  __syncthreads();
  const int lane = threadIdx.x & 63;
  const int wv = threadIdx.x >> 6;      // 0..7
  const int g4 = lane >> 4, q = lane & 15;
  const float4* __restrict__ h4 = reinterpret_cast<const float4*>(h);

  for (int r = blockIdx.x * 8 + wv; r < NN; r += 8192) {
    const int dg = deg[r];
    int myadj = (lane < dg) ? ell[(size_t)r * ELLW + lane] : 0;

    // 4 independent float4 chains; each (chain,group) slot = one edge row.
    // i<dg is uniform across each 16-lane group -> exec-masked load, no
    // memory request for invalid slots.
    float ax = 0.f, ay = 0.f, az = 0.f, aw = 0.f;
    float bx = 0.f, by = 0.f, bz = 0.f, bw = 0.f;
    float cx = 0.f, cy = 0.f, cz = 0.f, cw = 0.f;
    float dx = 0.f, dy = 0.f, dz = 0.f, dw = 0.f;
    for (int base = 0; base < dg; base += 16) {
      int i0 = base + g4, i1 = base + 4 + g4, i2 = base + 8 + g4, i3 = base + 12 + g4;
      int s0 = __shfl(myadj, i0 & 63, 64), s1 = __shfl(myadj, i1 & 63, 64);
      int s2 = __shfl(myadj, i2 & 63, 64), s3 = __shfl(myadj, i3 & 63, 64);
      float4 t0 = make_float4(0.f, 0.f, 0.f, 0.f);
      float4 t1 = t0, t2 = t0, t3 = t0;
      if (i0 < dg) t0 = h4[(size_t)s0 * 16 + q];
      if (i1 < dg) t1 = h4[(size_t)s1 * 16 + q];
      if (i2 < dg) t2 = h4[(size_t)s2 * 16 + q];
      if (i3 < dg) t3 = h4[(size_t)s3 * 16 + q];
      ax += t0.x; ay += t0.y; az += t0.z; aw += t0.w;
      bx += t1.x; by += t1.y; bz += t1.z; bw += t1.w;
      cx += t2.x; cy += t2.y; cz += t2.z; cw += t2.w;
      dx += t3.x; dy += t3.y; dz += t3.z; dw += t3.w;
    }
    float sx = (ax + bx) + (cx + dx), sy = (ay + by) + (cy + dy);
    float sz = (az + bz) + (cz + dz), sw = (aw + bw) + (cw + dw);
    // reduce across the 4 row-groups (lanes xor 16, 32)
    sx += __shfl_xor(sx, 16, 64); sy += __shfl_xor(sy, 16, 64);
    sz += __shfl_xor(sz, 16, 64); sw += __shfl_xor(sw, 16, 64);
    sx += __shfl_xor(sx, 32, 64); sy += __shfl_xor(sy, 32, 64);
    sz += __shfl_xor(sz, 32, 64); sw += __shfl_xor(sw, 32, 64);
    // self row ((1+eps)*x, eps=0)
    float4 self = h4[(size_t)r * 16 + q];
    sx += self.x; sy += self.y; sz += self.z; sw += self.w;
    // lane l now holds agg features [4q .. 4q+3] (q = l&15)

    // GEMM1 (+folded BN) + ReLU: feature 4*k4+j lives in lane k4 (sx..sw)
    float c0 = lba[lane], c1 = 0.f;
#pragma unroll
    for (int k4 = 0; k4 < 16; ++k4) {
      float r0 = __shfl(sx, k4, 64), r1 = __shfl(sy, k4, 64);
      float r2 = __shfl(sz, k4, 64), r3 = __shfl(sw, k4, 64);
      c0 = fmaf(r0, lA[(k4 * 4 + 0) * 64 + lane], c0);
      c1 = fmaf(r1, lA[(k4 * 4 + 1) * 64 + lane], c1);
      c0 = fmaf(r2, lA[(k4 * 4 + 2) * 64 + lane], c0);
      c1 = fmaf(r3, lA[(k4 * 4 + 3) * 64 + lane], c1);
    }
    float z = fmaxf(c0 + c1, 0.f);
    // GEMM2 + ReLU
    float d0 = lbb[lane], d1 = 0.f;
#pragma unroll
    for (int k = 0; k < 64; k += 2) {
      d0 = fmaf(__shfl(z, k, 64),     lB[k * 64 + lane],       d0);
      d1 = fmaf(__shfl(z, k + 1, 64), lB[(k + 1) * 64 + lane], d1);
    }
    hout[(size_t)r * 64 + lane] = fmaxf(d0 + d1, 0.f);
  }
}

// ---- head: hh = relu(h @ Wl1 + bl1)  [N,32]; also ps/pd = hh @ Wl2 halves
__global__ __launch_bounds__(256) void head(const float* __restrict__ h,
                                            const float* __restrict__ Wl1,
                                            const float* __restrict__ bl1,
                                            const float* __restrict__ Wl2,
                                            float* __restrict__ hh,
                                            float* __restrict__ ps,
                                            float* __restrict__ pd) {
  __shared__ float lW[2048], lb[32], lW2[384], lrows[512], lhh[256];
  for (int i = threadIdx.x; i < 2048; i += 256) lW[i] = Wl1[i];
  if (threadIdx.x < 32) lb[threadIdx.x] = bl1[threadIdx.x];
  for (int i = threadIdx.x; i < 384; i += 256) lW2[i] = Wl2[i];
  const int j = threadIdx.x & 31, rl = threadIdx.x >> 5;
  for (int rb = blockIdx.x * 8; rb < NN; rb += gridDim.x * 8) {
    __syncthreads();
    lrows[threadIdx.x]       = h[(size_t)rb * 64 + threadIdx.x];
    lrows[threadIdx.x + 256] = h[(size_t)rb * 64 + 256 + threadIdx.x];
    __syncthreads();
    float acc = lb[j];
#pragma unroll
    for (int k = 0; k < 64; ++k) acc = fmaf(lrows[rl * 64 + k], lW[k * 32 + j], acc);
    acc = fmaxf(acc, 0.f);
    hh[(size_t)(rb + rl) * 32 + j] = acc;
    lhh[rl * 32 + j] = acc;
    __syncthreads();
    // ps/pd: 96 dots of length 32
    if (threadIdx.x < 96) {
      int rr = threadIdx.x / 12, cc = threadIdx.x % 12;
      const float* wcol = (cc < 6) ? (lW2 + cc) : (lW2 + 192 + (cc - 6));
      float s = 0.f;
#pragma unroll
      for (int k = 0; k < 32; ++k) s = fmaf(lhh[rr * 32 + k], wcol[k * 6], s);
      if (cc < 6) ps[(size_t)(rb + rr) * 6 + cc] = s;
      else        pd[(size_t)(rb + rr) * 6 + cc - 6] = s;
    }
  }
}

// ---------------- edge epilogue: eo = [hh[src], hh[dst]]; out = ps[s]+pd[d]+b
__global__ __launch_bounds__(256) void edge_out(const float4* __restrict__ hh4,
                                                const int* __restrict__ src,
                                                const int* __restrict__ dst,
                                                const float* __restrict__ ps,
                                                const float* __restrict__ pd,
                                                const float* __restrict__ bl2,
                                                float* __restrict__ out,
                                                float4* __restrict__ eo4) {
  __shared__ float lb[6];
  if (threadIdx.x < 6) lb[threadIdx.x] = bl2[threadIdx.x];
  __syncthreads();
  const int lane = threadIdx.x & 63;
  const int wv = threadIdx.x >> 6;
  const int le = lane >> 4, q = lane & 15;
  for (int base = blockIdx.x * 16; base < EE; base += gridDim.x * 16) {
    const int ebase = base + wv * 4;
    const int e = ebase + le;
    int s = src[e], d = dst[e];
    float4 v = (q < 8) ? hh4[(size_t)s * 8 + q] : hh4[(size_t)d * 8 + (q - 8)];
    eo4[(size_t)e * 16 + q] = v;
    if (lane < 24) {
      int le2 = lane / 6, c = lane - 6 * le2;
      int e2 = ebase + le2;
      int s2 = src[e2], d2 = dst[e2];
      out[(size_t)ebase * 6 + lane] = ps[(size_t)s2 * 6 + c] + pd[(size_t)d2 * 6 + c] + lb[c];
    }
  }
}

extern "C" void kernel_launch(void* const* d_in, const int* in_sizes, int n_in,
                              void* d_out, int out_size, void* d_ws, size_t ws_size,
                              hipStream_t stream) {
  const float* x   = (const float*)d_in[0];
  const int*   ei  = (const int*)d_in[1];
  const float* W1  = (const float*)d_in[3];
  const float* b1  = (const float*)d_in[4];
  const float* g1  = (const float*)d_in[5];
  const float* be1 = (const float*)d_in[6];
  const float* W2  = (const float*)d_in[7];
  const float* b2  = (const float*)d_in[8];
  const float* Wa  = (const float*)d_in[9];
  const float* ba  = (const float*)d_in[10];
  const float* ga  = (const float*)d_in[11];
  const float* bea = (const float*)d_in[12];
  const float* Wb  = (const float*)d_in[13];
  const float* bb  = (const float*)d_in[14];
  const float* Wl1 = (const float*)d_in[15];
  const float* bl1 = (const float*)d_in[16];
  const float* Wl2 = (const float*)d_in[17];
  const float* bl2 = (const float*)d_in[18];

  const int* srcI = ei;
  const int* dstI = ei + EE;

  int* deg = (int*)d_ws;                       // NN
  int* ell = deg + NN;                         // NN*ELLW
  size_t int_end = (size_t)NN + (size_t)NN * ELLW;
  int_end = (int_end + 3) & ~(size_t)3;
  float* hA = (float*)d_ws + int_end;          // NN*64
  float* hB = hA + (size_t)NN * 64;            // NN*64
  float* hh = hB + (size_t)NN * 64;            // NN*32
  float* ps = hh + (size_t)NN * 32;            // NN*6
  float* pd = ps + (size_t)NN * 6;             // NN*6

  float* outp = (float*)d_out;                 // E*6
  float* eo   = outp + (size_t)EE * 6;         // E*64

  // ---- build ELL (dst -> list of src) once per launch
  zero_i32<<<(NN + 255) / 256, 256, 0, stream>>>(deg, NN);
  fill_ell<<<(EE + 255) / 256, 256, 0, stream>>>(srcI, dstI, deg, ell);

  // ---- 4 fused GIN layers (persistent: 1024 blocks x 8 waves)
  mlp_fused<<<1024, 512, 0, stream>>>(x, deg, ell, W1, b1, g1, be1, W2, b2, hA);
  const float* cur = hA;
  float* nxt = hB;
  for (int i = 0; i < 3; ++i) {
    mlp_fused<<<1024, 512, 0, stream>>>(cur, deg, ell,
                                        Wa + (size_t)i * 4096, ba + i * 64,
                                        ga + i * 64, bea + i * 64,
                                        Wb + (size_t)i * 4096, bb + i * 64, nxt);
    float* t = (float*)cur; cur = nxt; nxt = t;
  }

  head<<<2048, 256, 0, stream>>>(cur, Wl1, bl1, Wl2, hh, ps, pd);
  edge_out<<<8192, 256, 0, stream>>>((const float4*)hh, srcI, dstI, ps, pd, bl2,
                                     outp, (float4*)eo);
}

// Round 14
// 640.820 us; speedup vs baseline: 1.2506x; 1.2506x over previous
//
#include <hip/hip_runtime.h>

#define NN 50000
#define EE 800000
#define ELLW 64
#define BN_EPS 1e-5f

// ---------------------------------------------------------------- zero ints
__global__ __launch_bounds__(256) void zero_i32(int* __restrict__ p, int n) {
  int i = blockIdx.x * 256 + threadIdx.x;
  if (i < n) p[i] = 0;
}

// ------------------------------------- build ELL: ell[d][pos] = s, deg[d]++
__global__ __launch_bounds__(256) void fill_ell(const int* __restrict__ src,
                                                const int* __restrict__ dst,
                                                int* __restrict__ deg,
                                                int* __restrict__ ell) {
  int e = blockIdx.x * 256 + threadIdx.x;
  if (e < EE) {
    int d = dst[e];
    int pos = atomicAdd(&deg[d], 1);
    if (pos < ELLW) ell[(size_t)d * ELLW + pos] = src[e];
  }
}

// -------- fused: agg = h + sum_{in-edges} h[src];  hout = MLP(agg)
// DS-pipe-minimal GEMM: weights live in per-lane VGPRs (lane = output
// feature); agg/z staged in a per-wave LDS slot and consumed via
// wave-uniform ds_read_b128 broadcasts. ~48 DS instr/node vs ~270 before.
__global__ __launch_bounds__(256, 2) void mlp_fused(const float* __restrict__ h,
                                                    const int* __restrict__ deg,
                                                    const int* __restrict__ ell,
                                                    const float* __restrict__ Wa,
                                                    const float* __restrict__ ba,
                                                    const float* __restrict__ g,
                                                    const float* __restrict__ be,
                                                    const float* __restrict__ Wb,
                                                    const float* __restrict__ bb,
                                                    float* __restrict__ hout) {
  __shared__ float4 xs4[4][16];   // per-wave agg vector (64 floats)
  __shared__ float  zs[4][64];    // per-wave z vector
  const int lane = threadIdx.x & 63;
  const int wv = threadIdx.x >> 6;     // 0..3

  // per-lane weight columns, BN folded into W1 column + bias
  const float scl = g[lane] * rsqrtf(1.0f + BN_EPS);
  float w1[64], w2[64];
#pragma unroll
  for (int k = 0; k < 64; ++k) w1[k] = Wa[k * 64 + lane] * scl;   // coalesced
#pragma unroll
  for (int k = 0; k < 64; ++k) w2[k] = Wb[k * 64 + lane];
  const float bia = fmaf(ba[lane], scl, be[lane]);
  const float bib = bb[lane];

  const int g4 = lane >> 4, q = lane & 15;
  const float4* __restrict__ h4 = reinterpret_cast<const float4*>(h);

  for (int r = blockIdx.x * 4 + wv; r < NN; r += gridDim.x * 4) {
    const int dg = deg[r];
    int myadj = (lane < dg) ? ell[(size_t)r * ELLW + lane] : 0;

    // predicated float4 gather, 4 independent chains (R9/R11 structure)
    float ax = 0.f, ay = 0.f, az = 0.f, aw = 0.f;
    float bx = 0.f, by = 0.f, bz = 0.f, bw = 0.f;
    float cx = 0.f, cy = 0.f, cz = 0.f, cw = 0.f;
    float dx = 0.f, dy = 0.f, dz = 0.f, dw = 0.f;
    for (int base = 0; base < dg; base += 16) {
      int i0 = base + g4, i1 = base + 4 + g4, i2 = base + 8 + g4, i3 = base + 12 + g4;
      int s0 = __shfl(myadj, i0 & 63, 64), s1 = __shfl(myadj, i1 & 63, 64);
      int s2 = __shfl(myadj, i2 & 63, 64), s3 = __shfl(myadj, i3 & 63, 64);
      float4 t0 = make_float4(0.f, 0.f, 0.f, 0.f);
      float4 t1 = t0, t2 = t0, t3 = t0;
      if (i0 < dg) t0 = h4[(size_t)s0 * 16 + q];
      if (i1 < dg) t1 = h4[(size_t)s1 * 16 + q];
      if (i2 < dg) t2 = h4[(size_t)s2 * 16 + q];
      if (i3 < dg) t3 = h4[(size_t)s3 * 16 + q];
      ax += t0.x; ay += t0.y; az += t0.z; aw += t0.w;
      bx += t1.x; by += t1.y; bz += t1.z; bw += t1.w;
      cx += t2.x; cy += t2.y; cz += t2.z; cw += t2.w;
      dx += t3.x; dy += t3.y; dz += t3.z; dw += t3.w;
    }
    float sx = (ax + bx) + (cx + dx), sy = (ay + by) + (cy + dy);
    float sz = (az + bz) + (cz + dz), sw = (aw + bw) + (cw + dw);
    sx += __shfl_xor(sx, 16, 64); sy += __shfl_xor(sy, 16, 64);
    sz += __shfl_xor(sz, 16, 64); sw += __shfl_xor(sw, 16, 64);
    sx += __shfl_xor(sx, 32, 64); sy += __shfl_xor(sy, 32, 64);
    sz += __shfl_xor(sz, 32, 64); sw += __shfl_xor(sw, 32, 64);
    float4 self = h4[(size_t)r * 16 + q];
    sx += self.x; sy += self.y; sz += self.z; sw += self.w;
    // lane q (dup across groups) holds agg[4q..4q+3]; stage once per wave
    if (lane < 16) xs4[wv][q] = make_float4(sx, sy, sz, sw);

    // GEMM1 (+folded BN) + ReLU: b128 broadcast x, register weights
    float c0 = bia, c1 = 0.f, c2 = 0.f, c3 = 0.f;
#pragma unroll
    for (int k4 = 0; k4 < 16; ++k4) {
      float4 xv = xs4[wv][k4];
      c0 = fmaf(xv.x, w1[4 * k4 + 0], c0);
      c1 = fmaf(xv.y, w1[4 * k4 + 1], c1);
      c2 = fmaf(xv.z, w1[4 * k4 + 2], c2);
      c3 = fmaf(xv.w, w1[4 * k4 + 3], c3);
    }
    float z = fmaxf((c0 + c1) + (c2 + c3), 0.f);
    zs[wv][lane] = z;
    const float4* zp = reinterpret_cast<const float4*>(zs[wv]);

    // GEMM2 + ReLU
    float d0 = bib, d1 = 0.f, d2 = 0.f, d3 = 0.f;
#pragma unroll
    for (int k4 = 0; k4 < 16; ++k4) {
      float4 zv = zp[k4];
      d0 = fmaf(zv.x, w2[4 * k4 + 0], d0);
      d1 = fmaf(zv.y, w2[4 * k4 + 1], d1);
      d2 = fmaf(zv.z, w2[4 * k4 + 2], d2);
      d3 = fmaf(zv.w, w2[4 * k4 + 3], d3);
    }
    hout[(size_t)r * 64 + lane] = fmaxf((d0 + d1) + (d2 + d3), 0.f);
  }
}

// ---- head: hh = relu(h @ Wl1 + bl1)  [N,32]; also ps/pd = hh @ Wl2 halves
__global__ __launch_bounds__(256) void head(const float* __restrict__ h,
                                            const float* __restrict__ Wl1,
                                            const float* __restrict__ bl1,
                                            const float* __restrict__ Wl2,
                                            float* __restrict__ hh,
                                            float* __restrict__ ps,
                                            float* __restrict__ pd) {
  __shared__ float lW[2048], lb[32], lW2[384], lrows[512], lhh[256];
  for (int i = threadIdx.x; i < 2048; i += 256) lW[i] = Wl1[i];
  if (threadIdx.x < 32) lb[threadIdx.x] = bl1[threadIdx.x];
  for (int i = threadIdx.x; i < 384; i += 256) lW2[i] = Wl2[i];
  const int j = threadIdx.x & 31, rl = threadIdx.x >> 5;
  for (int rb = blockIdx.x * 8; rb < NN; rb += gridDim.x * 8) {
    __syncthreads();
    lrows[threadIdx.x]       = h[(size_t)rb * 64 + threadIdx.x];
    lrows[threadIdx.x + 256] = h[(size_t)rb * 64 + 256 + threadIdx.x];
    __syncthreads();
    float acc = lb[j];
#pragma unroll
    for (int k = 0; k < 64; ++k) acc = fmaf(lrows[rl * 64 + k], lW[k * 32 + j], acc);
    acc = fmaxf(acc, 0.f);
    hh[(size_t)(rb + rl) * 32 + j] = acc;
    lhh[rl * 32 + j] = acc;
    __syncthreads();
    // ps/pd: 96 dots of length 32
    if (threadIdx.x < 96) {
      int rr = threadIdx.x / 12, cc = threadIdx.x % 12;
      const float* wcol = (cc < 6) ? (lW2 + cc) : (lW2 + 192 + (cc - 6));
      float s = 0.f;
#pragma unroll
      for (int k = 0; k < 32; ++k) s = fmaf(lhh[rr * 32 + k], wcol[k * 6], s);
      if (cc < 6) ps[(size_t)(rb + rr) * 6 + cc] = s;
      else        pd[(size_t)(rb + rr) * 6 + cc - 6] = s;
    }
  }
}

// ---------------- edge epilogue: eo = [hh[src], hh[dst]]; out = ps[s]+pd[d]+b
__global__ __launch_bounds__(256) void edge_out(const float4* __restrict__ hh4,
                                                const int* __restrict__ src,
                                                const int* __restrict__ dst,
                                                const float* __restrict__ ps,
                                                const float* __restrict__ pd,
                                                const float* __restrict__ bl2,
                                                float* __restrict__ out,
                                                float4* __restrict__ eo4) {
  __shared__ float lb[6];
  if (threadIdx.x < 6) lb[threadIdx.x] = bl2[threadIdx.x];
  __syncthreads();
  const int lane = threadIdx.x & 63;
  const int wv = threadIdx.x >> 6;
  const int le = lane >> 4, q = lane & 15;
  for (int base = blockIdx.x * 16; base < EE; base += gridDim.x * 16) {
    const int ebase = base + wv * 4;
    const int e = ebase + le;
    int s = src[e], d = dst[e];
    float4 v = (q < 8) ? hh4[(size_t)s * 8 + q] : hh4[(size_t)d * 8 + (q - 8)];
    eo4[(size_t)e * 16 + q] = v;
    if (lane < 24) {
      int le2 = lane / 6, c = lane - 6 * le2;
      int e2 = ebase + le2;
      int s2 = src[e2], d2 = dst[e2];
      out[(size_t)ebase * 6 + lane] = ps[(size_t)s2 * 6 + c] + pd[(size_t)d2 * 6 + c] + lb[c];
    }
  }
}

extern "C" void kernel_launch(void* const* d_in, const int* in_sizes, int n_in,
                              void* d_out, int out_size, void* d_ws, size_t ws_size,
                              hipStream_t stream) {
  const float* x   = (const float*)d_in[0];
  const int*   ei  = (const int*)d_in[1];
  const float* W1  = (const float*)d_in[3];
  const float* b1  = (const float*)d_in[4];
  const float* g1  = (const float*)d_in[5];
  const float* be1 = (const float*)d_in[6];
  const float* W2  = (const float*)d_in[7];
  const float* b2  = (const float*)d_in[8];
  const float* Wa  = (const float*)d_in[9];
  const float* ba  = (const float*)d_in[10];
  const float* ga  = (const float*)d_in[11];
  const float* bea = (const float*)d_in[12];
  const float* Wb  = (const float*)d_in[13];
  const float* bb  = (const float*)d_in[14];
  const float* Wl1 = (const float*)d_in[15];
  const float* bl1 = (const float*)d_in[16];
  const float* Wl2 = (const float*)d_in[17];
  const float* bl2 = (const float*)d_in[18];

  const int* srcI = ei;
  const int* dstI = ei + EE;

  int* deg = (int*)d_ws;                       // NN
  int* ell = deg + NN;                         // NN*ELLW
  size_t int_end = (size_t)NN + (size_t)NN * ELLW;
  int_end = (int_end + 3) & ~(size_t)3;
  float* hA = (float*)d_ws + int_end;          // NN*64
  float* hB = hA + (size_t)NN * 64;            // NN*64
  float* hh = hB + (size_t)NN * 64;            // NN*32
  float* ps = hh + (size_t)NN * 32;            // NN*6
  float* pd = ps + (size_t)NN * 6;             // NN*6

  float* outp = (float*)d_out;                 // E*6
  float* eo   = outp + (size_t)EE * 6;         // E*64

  // ---- build ELL (dst -> list of src) once per launch
  zero_i32<<<(NN + 255) / 256, 256, 0, stream>>>(deg, NN);
  fill_ell<<<(EE + 255) / 256, 256, 0, stream>>>(srcI, dstI, deg, ell);

  // ---- 4 fused GIN layers (512 blocks x 4 waves, grid-stride)
  mlp_fused<<<512, 256, 0, stream>>>(x, deg, ell, W1, b1, g1, be1, W2, b2, hA);
  const float* cur = hA;
  float* nxt = hB;
  for (int i = 0; i < 3; ++i) {
    mlp_fused<<<512, 256, 0, stream>>>(cur, deg, ell,
                                       Wa + (size_t)i * 4096, ba + i * 64,
                                       ga + i * 64, bea + i * 64,
                                       Wb + (size_t)i * 4096, bb + i * 64, nxt);
    float* t = (float*)cur; cur = nxt; nxt = t;
  }

  head<<<2048, 256, 0, stream>>>(cur, Wl1, bl1, Wl2, hh, ps, pd);
  edge_out<<<8192, 256, 0, stream>>>((const float4*)hh, srcI, dstI, ps, pd, bl2,
                                     outp, (float4*)eo);
}